// Round 12
// baseline (305.709 us; speedup 1.0000x reference)
//
#include <hip/hip_runtime.h>
#include <stdint.h>

// Problem dims
#define BDIM 8
#define CDIM 32
#define NDIM 512
#define TDIM 168
#define KG   2048          // GEMM K = 4 slices * 512 nodes
#define NJ   43008         // 1344 (b,l) * 32 o   (column order jj = (b*168+l)*32 + o)
#define ALPHA_ 0.05f
#define BETA_  0.95f

typedef __attribute__((ext_vector_type(8))) short short8;
typedef __attribute__((ext_vector_type(4))) float f32x4;
typedef __attribute__((ext_vector_type(2))) float f2v;
typedef __attribute__((ext_vector_type(4))) unsigned short u16x4;

__device__ __forceinline__ unsigned short f2bf(float f) {
  union { float f; unsigned int u; } v; v.f = f;
  unsigned int r = v.u + 0x7fffu + ((v.u >> 16) & 1u);
  return (unsigned short)(r >> 16);
}
__device__ __forceinline__ float bf2f(unsigned short h) {
  union { unsigned int u; float f; } v; v.u = ((unsigned int)h) << 16;
  return v.f;
}
__device__ __forceinline__ void gload_lds16(const void* g, void* l) {
  __builtin_amdgcn_global_load_lds((const __attribute__((address_space(1))) void*)g,
                                   (__attribute__((address_space(3))) void*)l, 16, 0, 0);
}

// ---- prep: row sums of (adp + I) and (adp^T + I) ----
__global__ void gc_prep(const float* __restrict__ adp, float* __restrict__ rs) {
  int v = blockIdx.x, t = threadIdx.x;
  float sA = 0.f, sB = 0.f;
  for (int w = t; w < NDIM; w += 256) { sA += adp[v * NDIM + w]; sB += adp[w * NDIM + v]; }
  __shared__ float red[2][256];
  red[0][t] = sA; red[1][t] = sB; __syncthreads();
  for (int s = 128; s > 0; s >>= 1) {
    if (t < s) { red[0][t] += red[0][t + s]; red[1][t] += red[1][t + s]; }
    __syncthreads();
  }
  if (t == 0) { rs[v] = 1.f + red[0][0]; rs[NDIM + v] = 1.f + red[1][0]; }
}

// ---- build A (slice 0) and A' (slice 2) into chunked G2[(k>>3)][n][8], plus fp32 copies ----
__global__ void gc_build(const float* __restrict__ adp, const float* __restrict__ rs,
                         float* __restrict__ Af, unsigned short* __restrict__ G2) {
  int v = blockIdx.x, t = threadIdx.x;
  float ra = 1.f / rs[v], rb = 1.f / rs[NDIM + v];
  for (int w = t; w < NDIM; w += 256) {
    float d = (v == w) ? 1.f : 0.f;
    float a  = (adp[v * NDIM + w] + d) * ra;   // A[v][w]
    float a2 = (adp[w * NDIM + v] + d) * rb;   // A'[v][w]
    Af[(size_t)v * NDIM + w] = a;
    Af[(size_t)NDIM * NDIM + (size_t)v * NDIM + w] = a2;
    G2[(size_t)(((0 * 64) + (w >> 3)) * 512 + v) * 8 + (w & 7)] = f2bf(a);
    G2[(size_t)(((2 * 64) + (w >> 3)) * 512 + v) * 8 + (w & 7)] = f2bf(a2);
  }
}

// ---- A^2 (slice 1) and A'^2 (slice 3) into G2; 512 blocks of 32x32 tiles ----
__global__ __launch_bounds__(256, 4) void gc_sq2(const float* __restrict__ Af,
                                                 unsigned short* __restrict__ G2) {
  int bid = blockIdx.x;
  int mat = bid >> 8, tile = bid & 255;
  int v0 = (tile >> 4) * 32, w0 = (tile & 15) * 32;
  const float* M = Af + (size_t)mat * NDIM * NDIM;
  __shared__ float T1[64][33];
  __shared__ float T2[64][33];
  int t = threadIdx.x;
  int ty = t >> 4, tx = t & 15;
  float a00 = 0.f, a01 = 0.f, a10 = 0.f, a11 = 0.f;
  for (int u0 = 0; u0 < NDIM; u0 += 64) {
    #pragma unroll
    for (int q = 0; q < 8; ++q) {
      int id = q * 256 + t;
      int c = id & 63, r = id >> 6;
      T1[c][r] = M[(size_t)(v0 + r) * NDIM + u0 + c];
      int u = id >> 5, w = id & 31;
      T2[u][w] = M[(size_t)(u0 + u) * NDIM + w0 + w];
    }
    __syncthreads();
    for (int u = 0; u < 64; ++u) {
      f2v a = *(const f2v*)&T1[u][ty * 2];
      f2v b = *(const f2v*)&T2[u][tx * 2];
      a00 += a[0] * b[0]; a01 += a[0] * b[1];
      a10 += a[1] * b[0]; a11 += a[1] * b[1];
    }
    __syncthreads();
  }
  int sl = mat ? 3 : 1;
  int v = v0 + ty * 2, w = w0 + tx * 2;
  size_t cb = (size_t)(sl * 64 + (w >> 3)) * 512;
  size_t cb1 = (size_t)(sl * 64 + ((w + 1) >> 3)) * 512;
  G2[(cb  + v    ) * 8 + (w & 7)]       = f2bf(a00);
  G2[(cb1 + v    ) * 8 + ((w + 1) & 7)] = f2bf(a01);
  G2[(cb  + v + 1) * 8 + (w & 7)]       = f2bf(a10);
  G2[(cb1 + v + 1) * 8 + ((w + 1) & 7)] = f2bf(a11);
}

// ---- folded channel-mix matrices, bf16: Ub[160][32] rows = {U1,U2,V1,V2,U0'}; bias = b1+b2 ----
__global__ void gc_ucat(const float* __restrict__ W1, const float* __restrict__ b1,
                        const float* __restrict__ W2, const float* __restrict__ b2,
                        unsigned short* __restrict__ Ub, float* __restrict__ bias) {
  int t = threadIdx.x;
  for (int idx = t; idx < 160 * 32; idx += 256) {
    int ko = idx >> 5, c = idx & 31, o = ko & 31, s = ko >> 5;
    float v;
    if (s == 0)      v = BETA_ * (W1[o * 96 + 32 + c] + ALPHA_ * W1[o * 96 + 64 + c]);
    else if (s == 1) v = BETA_ * BETA_ * W1[o * 96 + 64 + c];
    else if (s == 2) v = BETA_ * (W2[o * 96 + 32 + c] + ALPHA_ * W2[o * 96 + 64 + c]);
    else if (s == 3) v = BETA_ * BETA_ * W2[o * 96 + 64 + c];
    else             v = W1[o * 96 + c] + ALPHA_ * (W1[o * 96 + 32 + c] + W1[o * 96 + 64 + c])
                       + W2[o * 96 + c] + ALPHA_ * (W2[o * 96 + 32 + c] + W2[o * 96 + 64 + c]);
    Ub[idx] = f2bf(v);
  }
  if (t < 32) bias[t] = b1[t] + b2[t];
}

// ---- channel-mix via MFMA, direct stores in (b,l,o)-major column order ----
// Pg[kbg 0..320)[jj][8w]; slices 0..3 = GEMM B-panel, slice 4 = identity (old R0).
// grid 1024 = 8 b * 32 wt(16 w) * 4 lq(42 l); 256 threads (4 waves)
__global__ __launch_bounds__(256, 2) void gc_mix6(const float* __restrict__ x,
    const unsigned short* __restrict__ Ub, unsigned short* __restrict__ Pg) {
  __shared__ __align__(16) unsigned short xs[26880];  // [42 ll][16 w'][40 c pad]
  int bid = blockIdx.x;
  int lq = bid & 3, wt = (bid >> 2) & 31, b = bid >> 7;
  int l0 = lq * 42, w0 = wt * 16;
  int tid = threadIdx.x, wv = tid >> 6, lane = tid & 63;
  int l15 = lane & 15, hi = lane >> 4;

  // stage x[b][:][w0..w0+16)[l0..l0+42) -> xs (coalesced reads, swizzled 2B writes)
  #pragma unroll 4
  for (int e = 0; e < 84; ++e) {
    int id = e * 256 + tid;
    int c = id / 672, rem = id - c * 672;
    int w = rem / 42, ll = rem - w * 42;
    float v = x[(size_t)((b * 32 + c) * 512 + w0 + w) * 168 + l0 + ll];
    xs[(ll * 16 + (w ^ (ll & 15))) * 40 + c] = f2bf(v);
  }
  __syncthreads();

  // B-operand fragments from Ub (col=l15 -> o, k=hi*8.. -> c)
  short8 uF[10];
  #pragma unroll
  for (int mt = 0; mt < 10; ++mt)
    uF[mt] = *(const short8*)(Ub + (size_t)(mt * 16 + l15) * 32 + hi * 8);

  for (int i = 0; i < 11; ++i) {
    int li = wv + 4 * i;
    if (li >= 42) break;
    int l = l0 + li;
    short8 xf = *(const short8*)&xs[(li * 16 + (l15 ^ (li & 15))) * 40 + hi * 8];
    size_t jbase = (size_t)(b * 168 + l) * 32;
    #pragma unroll
    for (int mt = 0; mt < 10; ++mt) {
      f32x4 z = {0.f, 0.f, 0.f, 0.f};
      f32x4 p = __builtin_amdgcn_mfma_f32_16x16x32_bf16(xf, uF[mt], z, 0, 0, 0);
      size_t kbg = (size_t)((mt >> 1) * 64 + wt * 2 + (hi >> 1));
      size_t jj = jbase + ((mt & 1) << 4) + l15;
      u16x4 pk = { f2bf(p[0]), f2bf(p[1]), f2bf(p[2]), f2bf(p[3]) };
      *(u16x4*)(Pg + (kbg * NJ + jj) * 8 + (hi & 1) * 4) = pk;
    }
  }
}

// ---- main GEMM, m97-faithful: 128x128 tile, 4 waves of 64x64, BK=32, 32KB dbuf,
// ONE __syncthreads per K-tile (compiler-drained), no pins, no setprio.
// 1344 blocks (4 nt * 336 jt) -> ~3 blocks/CU (12 waves/CU TLP). nt-group-of-4
// XCD swizzle: 4 blocks sharing a B-panel land on the same XCD (L2 reuse).
// Epilogue: LDS slab transpose; out = C + P4 + bias (16B l-run stores).
__global__ __launch_bounds__(256, 3) void gc_gemm12(const unsigned short* __restrict__ G2,
    const unsigned short* __restrict__ Pg, const float* __restrict__ bias,
    float* __restrict__ out) {
  int bid = blockIdx.x;
  int swz = (bid & 7) * 168 + (bid >> 3);  // XCD-chunked bijective swizzle (1344 = 8*168)
  int nt = swz & 3, jt = swz >> 2;         // nt fastest: B-panel quad adjacent on same XCD
  int n0 = nt * 128, jj0 = jt * 128;

  __shared__ __align__(16) unsigned short SH[16896];   // 33792 B (loop uses 32768)
  unsigned short* Ab = SH;                 // 2 bufs x [kb 4][n 128][8] = 2 x 4096
  unsigned short* Bb = SH + 8192;          // 2 bufs x [kb 4][j 128][8] = 2 x 4096

  int tid = threadIdx.x, lane = tid & 63, wid = tid >> 6;
  int wm = wid >> 1, wn = wid & 1;
  int l15 = lane & 15, hi = lane >> 4;

  // staging: 2 A-chunks + 2 B-chunks per thread (16B each)
  const unsigned short* srcA[2]; const unsigned short* srcB[2]; int dAB[2];
  #pragma unroll
  for (int q = 0; q < 2; ++q) {
    int f = q * 256 + tid;                 // kb = f>>7, loc = f&127
    srcA[q] = G2 + ((size_t)(f >> 7) * 512 + n0 + (f & 127)) * 8;
    srcB[q] = Pg + ((size_t)(f >> 7) * NJ + jj0 + (f & 127)) * 8;
    dAB[q] = f * 8;
  }
  const size_t strideA = 4 * 512 * 8;      // shorts per K-32 tile
  const size_t strideB = (size_t)4 * NJ * 8;

  f32x4 acc[4][4] = {};

  // stage tile 0 -> buf0
  #pragma unroll
  for (int q = 0; q < 2; ++q) {
    gload_lds16(srcA[q], Ab + dAB[q]);
    gload_lds16(srcB[q], Bb + dAB[q]);
  }
  __syncthreads();

  int aoffs = (wm * 64 + l15) * 8;
  int boffs = (wn * 64 + l15) * 8;

  for (int t = 0; t < 64; ++t) {
    const int cur = t & 1;
    if (t < 63) {                          // issue next tile into the other buffer
      #pragma unroll
      for (int q = 0; q < 2; ++q) {
        gload_lds16(srcA[q] + (size_t)(t + 1) * strideA, Ab + (cur ^ 1) * 4096 + dAB[q]);
        gload_lds16(srcB[q] + (size_t)(t + 1) * strideB, Bb + (cur ^ 1) * 4096 + dAB[q]);
      }
    }
    const unsigned short* ap = Ab + cur * 4096;
    const unsigned short* bp = Bb + cur * 4096;
    short8 aF[4], bF[4];
    #pragma unroll
    for (int mi = 0; mi < 4; ++mi)
      aF[mi] = *(const short8*)&ap[hi * 1024 + aoffs + mi * 128];
    #pragma unroll
    for (int nj = 0; nj < 4; ++nj)
      bF[nj] = *(const short8*)&bp[hi * 1024 + boffs + nj * 128];
    #pragma unroll
    for (int mi = 0; mi < 4; ++mi)
      #pragma unroll
      for (int nj = 0; nj < 4; ++nj)
        acc[mi][nj] = __builtin_amdgcn_mfma_f32_16x16x32_bf16(aF[mi], bF[nj], acc[mi][nj], 0, 0, 0);
    __syncthreads();                       // drains tile t+1 loads; WAR-safe swap
  }

  // ---- epilogue: 2 slabs of 64 n; LDS transpose; out = C + P4 + bias ----
  int bl0 = jt * 4;                        // 4 consecutive (b,l), same b (168%4==0)
  int bq = bl0 / 168, l0g = bl0 - bq * 168;
  float* Cs = (float*)SH;                  // 64*132*4 = 33792 B (exact fit)
  int o = tid & 31, nl8 = tid >> 5;        // o 0..31, nl8 0..7
  float bs = bias[o];
  for (int s = 0; s < 2; ++s) {
    if (wm == s) {
      #pragma unroll
      for (int mi = 0; mi < 4; ++mi)
        #pragma unroll
        for (int nj = 0; nj < 4; ++nj) {
          int row = mi * 16 + hi * 4;
          int col = wn * 64 + nj * 16 + l15;
          #pragma unroll
          for (int r = 0; r < 4; ++r)
            Cs[(row + r) * 132 + col] = acc[mi][nj][r];
        }
    }
    __syncthreads();
    int n_g0 = n0 + s * 64 + nl8 * 8;
    const unsigned short* p4c =
        Pg + (((size_t)256 + (n_g0 >> 3)) * NJ + (size_t)bl0 * 32 + o) * 8;
    short8 pv0 = *(const short8*)(p4c);
    short8 pv1 = *(const short8*)(p4c + 256);   // l+1 (jj stride 32 chunks)
    short8 pv2 = *(const short8*)(p4c + 512);   // l+2
    short8 pv3 = *(const short8*)(p4c + 768);   // l+3
    #pragma unroll
    for (int q = 0; q < 8; ++q) {
      int nr = nl8 * 8 + q;
      int n_g = n_g0 + q;
      float v0 = Cs[nr * 132 +  0 + o] + bf2f((unsigned short)pv0[q]) + bs;
      float v1 = Cs[nr * 132 + 32 + o] + bf2f((unsigned short)pv1[q]) + bs;
      float v2 = Cs[nr * 132 + 64 + o] + bf2f((unsigned short)pv2[q]) + bs;
      float v3 = Cs[nr * 132 + 96 + o] + bf2f((unsigned short)pv3[q]) + bs;
      f32x4 vv = {v0, v1, v2, v3};
      *(f32x4*)(out + ((size_t)(bq * 32 + o) * 512 + n_g) * 168 + l0g) = vv;
    }
    __syncthreads();
  }
}

extern "C" void kernel_launch(void* const* d_in, const int* in_sizes, int n_in,
                              void* d_out, int out_size, void* d_ws, size_t ws_size,
                              hipStream_t stream) {
  const float* x   = (const float*)d_in[0];
  const float* adp = (const float*)d_in[1];
  const float* W1  = (const float*)d_in[2];
  const float* b1  = (const float*)d_in[3];
  const float* W2  = (const float*)d_in[4];
  const float* b2  = (const float*)d_in[5];
  float* out = (float*)d_out;

  char* w = (char*)d_ws;
  unsigned short* Pg  = (unsigned short*)(w);                  // 220,200,960 B (5 slices)
  unsigned short* G2  = (unsigned short*)(w + 220200960ULL);   //   2,097,152 B
  float* Af           = (float*)(w + 222298112ULL);            //   2,097,152 B
  float* rs           = (float*)(w + 224395264ULL);            //       4,096 B
  unsigned short* Ub  = (unsigned short*)(w + 224399360ULL);   //      16,384 B (10,240 used)
  float* bias         = (float*)(w + 224415744ULL);            //         128 B
  if (ws_size < 224415872ULL) return;                          // need ~214 MiB

  gc_prep<<<512, 256, 0, stream>>>(adp, rs);
  gc_build<<<512, 256, 0, stream>>>(adp, rs, Af, G2);
  gc_sq2<<<512, 256, 0, stream>>>(Af, G2);
  gc_ucat<<<1, 256, 0, stream>>>(W1, b1, W2, b2, Ub, bias);
  gc_mix6<<<1024, 256, 0, stream>>>(x, Ub, Pg);
  gc_gemm12<<<1344, 256, 0, stream>>>(G2, Pg, bias, out);
}

// Round 13
// 297.050 us; speedup vs baseline: 1.0291x; 1.0291x over previous
//
#include <hip/hip_runtime.h>
#include <stdint.h>

// Problem dims
#define BDIM 8
#define CDIM 32
#define NDIM 512
#define TDIM 168
#define KG   2048          // GEMM K = 4 slices * 512 nodes
#define NJ   43008         // 1344 (b,l) * 32 o   (column order jj = (b*168+l)*32 + o)
#define ALPHA_ 0.05f
#define BETA_  0.95f

typedef __attribute__((ext_vector_type(8))) short short8;
typedef __attribute__((ext_vector_type(4))) float f32x4;
typedef __attribute__((ext_vector_type(2))) float f2v;
typedef __attribute__((ext_vector_type(4))) unsigned short u16x4;

__device__ __forceinline__ unsigned short f2bf(float f) {
  union { float f; unsigned int u; } v; v.f = f;
  unsigned int r = v.u + 0x7fffu + ((v.u >> 16) & 1u);
  return (unsigned short)(r >> 16);
}
__device__ __forceinline__ float bf2f(unsigned short h) {
  union { unsigned int u; float f; } v; v.u = ((unsigned int)h) << 16;
  return v.f;
}

// ---- fused prep+build (+ucat in block 512): row/col sums, normalized A/A' -> G2+Af ----
__global__ void gc_prep2(const float* __restrict__ adp,
                         const float* __restrict__ W1, const float* __restrict__ b1,
                         const float* __restrict__ W2, const float* __restrict__ b2,
                         float* __restrict__ Af, unsigned short* __restrict__ G2,
                         unsigned short* __restrict__ Ub, float* __restrict__ bias) {
  int t = threadIdx.x;
  if (blockIdx.x == 512) {   // ucat
    for (int idx = t; idx < 160 * 32; idx += 256) {
      int ko = idx >> 5, c = idx & 31, o = ko & 31, s = ko >> 5;
      float v;
      if (s == 0)      v = BETA_ * (W1[o * 96 + 32 + c] + ALPHA_ * W1[o * 96 + 64 + c]);
      else if (s == 1) v = BETA_ * BETA_ * W1[o * 96 + 64 + c];
      else if (s == 2) v = BETA_ * (W2[o * 96 + 32 + c] + ALPHA_ * W2[o * 96 + 64 + c]);
      else if (s == 3) v = BETA_ * BETA_ * W2[o * 96 + 64 + c];
      else             v = W1[o * 96 + c] + ALPHA_ * (W1[o * 96 + 32 + c] + W1[o * 96 + 64 + c])
                         + W2[o * 96 + c] + ALPHA_ * (W2[o * 96 + 32 + c] + W2[o * 96 + 64 + c]);
      Ub[idx] = f2bf(v);
    }
    if (t < 32) bias[t] = b1[t] + b2[t];
    return;
  }
  int v = blockIdx.x;
  float sA = 0.f, sB = 0.f;
  for (int w = t; w < NDIM; w += 256) { sA += adp[v * NDIM + w]; sB += adp[w * NDIM + v]; }
  __shared__ float red[2][256];
  red[0][t] = sA; red[1][t] = sB; __syncthreads();
  for (int s = 128; s > 0; s >>= 1) {
    if (t < s) { red[0][t] += red[0][t + s]; red[1][t] += red[1][t + s]; }
    __syncthreads();
  }
  float ra = 1.f / (1.f + red[0][0]);
  float rb = 1.f / (1.f + red[1][0]);
  for (int w = t; w < NDIM; w += 256) {
    float d = (v == w) ? 1.f : 0.f;
    float a  = (adp[v * NDIM + w] + d) * ra;   // A[v][w]
    float a2 = (adp[w * NDIM + v] + d) * rb;   // A'[v][w]
    Af[(size_t)v * NDIM + w] = a;
    Af[(size_t)NDIM * NDIM + (size_t)v * NDIM + w] = a2;
    G2[(size_t)(((0 * 64) + (w >> 3)) * 512 + v) * 8 + (w & 7)] = f2bf(a);
    G2[(size_t)(((2 * 64) + (w >> 3)) * 512 + v) * 8 + (w & 7)] = f2bf(a2);
  }
}

// ---- A^2 (slice 1) and A'^2 (slice 3) into G2; 512 blocks of 32x32 tiles ----
__global__ __launch_bounds__(256, 4) void gc_sq2(const float* __restrict__ Af,
                                                 unsigned short* __restrict__ G2) {
  int bid = blockIdx.x;
  int mat = bid >> 8, tile = bid & 255;
  int v0 = (tile >> 4) * 32, w0 = (tile & 15) * 32;
  const float* M = Af + (size_t)mat * NDIM * NDIM;
  __shared__ float T1[64][33];
  __shared__ float T2[64][33];
  int t = threadIdx.x;
  int ty = t >> 4, tx = t & 15;
  float a00 = 0.f, a01 = 0.f, a10 = 0.f, a11 = 0.f;
  for (int u0 = 0; u0 < NDIM; u0 += 64) {
    #pragma unroll
    for (int q = 0; q < 8; ++q) {
      int id = q * 256 + t;
      int c = id & 63, r = id >> 6;
      T1[c][r] = M[(size_t)(v0 + r) * NDIM + u0 + c];
      int u = id >> 5, w = id & 31;
      T2[u][w] = M[(size_t)(u0 + u) * NDIM + w0 + w];
    }
    __syncthreads();
    for (int u = 0; u < 64; ++u) {
      f2v a = *(const f2v*)&T1[u][ty * 2];
      f2v b = *(const f2v*)&T2[u][tx * 2];
      a00 += a[0] * b[0]; a01 += a[0] * b[1];
      a10 += a[1] * b[0]; a11 += a[1] * b[1];
    }
    __syncthreads();
  }
  int sl = mat ? 3 : 1;
  int v = v0 + ty * 2, w = w0 + tx * 2;
  size_t cb = (size_t)(sl * 64 + (w >> 3)) * 512;
  size_t cb1 = (size_t)(sl * 64 + ((w + 1) >> 3)) * 512;
  G2[(cb  + v    ) * 8 + (w & 7)]       = f2bf(a00);
  G2[(cb1 + v    ) * 8 + ((w + 1) & 7)] = f2bf(a01);
  G2[(cb  + v + 1) * 8 + (w & 7)]       = f2bf(a10);
  G2[(cb1 + v + 1) * 8 + ((w + 1) & 7)] = f2bf(a11);
}

// ---- channel-mix via MFMA, direct stores in (b,l,o)-major column order ----
// Pg[kbg 0..320)[jj][8w]; slices 0..3 = GEMM B-panel, slice 4 = identity (old R0).
// grid 1024 = 8 b * 32 wt(16 w) * 4 lq(42 l); 256 threads (4 waves)
__global__ __launch_bounds__(256, 2) void gc_mix6(const float* __restrict__ x,
    const unsigned short* __restrict__ Ub, unsigned short* __restrict__ Pg) {
  __shared__ __align__(16) unsigned short xs[26880];  // [42 ll][16 w'][40 c pad]
  int bid = blockIdx.x;
  int lq = bid & 3, wt = (bid >> 2) & 31, b = bid >> 7;
  int l0 = lq * 42, w0 = wt * 16;
  int tid = threadIdx.x, wv = tid >> 6, lane = tid & 63;
  int l15 = lane & 15, hi = lane >> 4;

  // stage x[b][:][w0..w0+16)[l0..l0+42) -> xs (coalesced reads, swizzled 2B writes)
  #pragma unroll 4
  for (int e = 0; e < 84; ++e) {
    int id = e * 256 + tid;
    int c = id / 672, rem = id - c * 672;
    int w = rem / 42, ll = rem - w * 42;
    float v = x[(size_t)((b * 32 + c) * 512 + w0 + w) * 168 + l0 + ll];
    xs[(ll * 16 + (w ^ (ll & 15))) * 40 + c] = f2bf(v);
  }
  __syncthreads();

  short8 uF[10];
  #pragma unroll
  for (int mt = 0; mt < 10; ++mt)
    uF[mt] = *(const short8*)(Ub + (size_t)(mt * 16 + l15) * 32 + hi * 8);

  for (int i = 0; i < 11; ++i) {
    int li = wv + 4 * i;
    if (li >= 42) break;
    int l = l0 + li;
    short8 xf = *(const short8*)&xs[(li * 16 + (l15 ^ (li & 15))) * 40 + hi * 8];
    size_t jbase = (size_t)(b * 168 + l) * 32;
    #pragma unroll
    for (int mt = 0; mt < 10; ++mt) {
      f32x4 z = {0.f, 0.f, 0.f, 0.f};
      f32x4 p = __builtin_amdgcn_mfma_f32_16x16x32_bf16(xf, uF[mt], z, 0, 0, 0);
      size_t kbg = (size_t)((mt >> 1) * 64 + wt * 2 + (hi >> 1));
      size_t jj = jbase + ((mt & 1) << 4) + l15;
      u16x4 pk = { f2bf(p[0]), f2bf(p[1]), f2bf(p[2]), f2bf(p[3]) };
      *(u16x4*)(Pg + (kbg * NJ + jj) * 8 + (hi & 1) * 4) = pk;
    }
  }
}

// ---- main GEMM: ZERO-SYNC direct-to-register loop (no LDS, no barriers) ----
// C[512 n][43008 jj] = G[512][2048] * P; both operand layouts are fragment-coalesced
// (16 lanes x 16B = 256B segments), so each lane loads its MFMA fragments straight
// from L2/L3 into VGPRs with an explicit 2-stage register pipeline (named sets).
// 672 blocks (2 mt * 336 jt), 256 threads = 4 waves (2M x 2N), wave tile 128x64.
// Regs: 128 acc + 96 frag + addr ~= 248 <= 256 @ (256,2). LDS only in epilogue.
__global__ __launch_bounds__(256, 2) void gc_gemm13(const unsigned short* __restrict__ G2,
    const unsigned short* __restrict__ Pg, const float* __restrict__ bias,
    float* __restrict__ out) {
  int bid = blockIdx.x;
  int swz = (bid & 7) * 84 + (bid >> 3);   // XCD-chunked bijective swizzle (672 = 8*84)
  int mt = swz & 1, jt = swz >> 1;         // mt fastest: A-panel pair adjacent on same XCD
  int n0 = mt * 256, jj0 = jt * 128;

  __shared__ __align__(16) unsigned short SH[16896];   // epilogue slab (33792 B)

  int tid = threadIdx.x, lane = tid & 63, wid = tid >> 6;
  int wm = wid >> 1, wn = wid & 1;
  int l15 = lane & 15, hi = lane >> 4;

  // per-lane fragment pointers for tile 0 (kb = hi)
  const unsigned short* pa[8];
  #pragma unroll
  for (int mi = 0; mi < 8; ++mi)
    pa[mi] = G2 + ((size_t)hi * 512 + n0 + wm * 128 + mi * 16 + l15) * 8;
  const unsigned short* pb[4];
  #pragma unroll
  for (int nj = 0; nj < 4; ++nj)
    pb[nj] = Pg + ((size_t)hi * NJ + jj0 + wn * 64 + nj * 16 + l15) * 8;
  const size_t sA = 4 * 512 * 8;           // shorts per K-32 tile
  const size_t sB = (size_t)4 * NJ * 8;

  f32x4 acc[8][4] = {};
  short8 a0[8], b0[4], a1[8], b1[4];

  // prologue: tile 0 -> set0
  #pragma unroll
  for (int mi = 0; mi < 8; ++mi) a0[mi] = *(const short8*)(pa[mi]);
  #pragma unroll
  for (int nj = 0; nj < 4; ++nj) b0[nj] = *(const short8*)(pb[nj]);

  for (int s = 0; s < 32; ++s) {
    // even body: issue tile 2s+1 -> set1, then MFMA set0 (loads land under MFMA)
    {
      size_t oA = (size_t)(2 * s + 1) * sA, oB = (size_t)(2 * s + 1) * sB;
      #pragma unroll
      for (int mi = 0; mi < 8; ++mi) a1[mi] = *(const short8*)(pa[mi] + oA);
      #pragma unroll
      for (int nj = 0; nj < 4; ++nj) b1[nj] = *(const short8*)(pb[nj] + oB);
    }
    __builtin_amdgcn_s_setprio(1);
    #pragma unroll
    for (int mi = 0; mi < 8; ++mi)
      #pragma unroll
      for (int nj = 0; nj < 4; ++nj)
        acc[mi][nj] = __builtin_amdgcn_mfma_f32_16x16x32_bf16(a0[mi], b0[nj], acc[mi][nj], 0, 0, 0);
    __builtin_amdgcn_s_setprio(0);

    // odd body: issue tile 2s+2 -> set0 (guarded), then MFMA set1
    if (s < 31) {
      size_t oA = (size_t)(2 * s + 2) * sA, oB = (size_t)(2 * s + 2) * sB;
      #pragma unroll
      for (int mi = 0; mi < 8; ++mi) a0[mi] = *(const short8*)(pa[mi] + oA);
      #pragma unroll
      for (int nj = 0; nj < 4; ++nj) b0[nj] = *(const short8*)(pb[nj] + oB);
    }
    __builtin_amdgcn_s_setprio(1);
    #pragma unroll
    for (int mi = 0; mi < 8; ++mi)
      #pragma unroll
      for (int nj = 0; nj < 4; ++nj)
        acc[mi][nj] = __builtin_amdgcn_mfma_f32_16x16x32_bf16(a1[mi], b1[nj], acc[mi][nj], 0, 0, 0);
    __builtin_amdgcn_s_setprio(0);
  }

  // ---- epilogue: 4 slabs of 64 n; LDS transpose; out = C + P4 + bias ----
  int bl0 = jt * 4;                        // 4 consecutive (b,l), same b (168%4==0)
  int bq = bl0 / 168, l0g = bl0 - bq * 168;
  float* Cs = (float*)SH;                  // 64*132*4 = 33792 B (exact fit)
  int o = tid & 31, nl8 = tid >> 5;        // o 0..31, nl8 0..7
  float bs = bias[o];
  __syncthreads();
  for (int s = 0; s < 4; ++s) {
    if (wm == (s >> 1)) {
      int mio = (s & 1) * 4;
      #pragma unroll
      for (int mi = 0; mi < 4; ++mi)
        #pragma unroll
        for (int nj = 0; nj < 4; ++nj) {
          int row = mi * 16 + hi * 4;
          int col = wn * 64 + nj * 16 + l15;
          #pragma unroll
          for (int r = 0; r < 4; ++r)
            Cs[(row + r) * 132 + col] = acc[mio + mi][nj][r];
        }
    }
    __syncthreads();
    int n_g0 = n0 + s * 64 + nl8 * 8;
    const unsigned short* p4c =
        Pg + (((size_t)256 + (n_g0 >> 3)) * NJ + (size_t)bl0 * 32 + o) * 8;
    short8 pv0 = *(const short8*)(p4c);
    short8 pv1 = *(const short8*)(p4c + 256);   // l+1 (jj stride 32 chunks)
    short8 pv2 = *(const short8*)(p4c + 512);   // l+2
    short8 pv3 = *(const short8*)(p4c + 768);   // l+3
    #pragma unroll
    for (int q = 0; q < 8; ++q) {
      int nr = nl8 * 8 + q;
      int n_g = n_g0 + q;
      float v0 = Cs[nr * 132 +  0 + o] + bf2f((unsigned short)pv0[q]) + bs;
      float v1 = Cs[nr * 132 + 32 + o] + bf2f((unsigned short)pv1[q]) + bs;
      float v2 = Cs[nr * 132 + 64 + o] + bf2f((unsigned short)pv2[q]) + bs;
      float v3 = Cs[nr * 132 + 96 + o] + bf2f((unsigned short)pv3[q]) + bs;
      f32x4 vv = {v0, v1, v2, v3};
      *(f32x4*)(out + ((size_t)(bq * 32 + o) * 512 + n_g) * 168 + l0g) = vv;
    }
    __syncthreads();
  }
}

extern "C" void kernel_launch(void* const* d_in, const int* in_sizes, int n_in,
                              void* d_out, int out_size, void* d_ws, size_t ws_size,
                              hipStream_t stream) {
  const float* x   = (const float*)d_in[0];
  const float* adp = (const float*)d_in[1];
  const float* W1  = (const float*)d_in[2];
  const float* b1  = (const float*)d_in[3];
  const float* W2  = (const float*)d_in[4];
  const float* b2  = (const float*)d_in[5];
  float* out = (float*)d_out;

  char* w = (char*)d_ws;
  unsigned short* Pg  = (unsigned short*)(w);                  // 220,200,960 B (5 slices)
  unsigned short* G2  = (unsigned short*)(w + 220200960ULL);   //   2,097,152 B
  float* Af           = (float*)(w + 222298112ULL);            //   2,097,152 B
  unsigned short* Ub  = (unsigned short*)(w + 224399360ULL);   //      16,384 B (10,240 used)
  float* bias         = (float*)(w + 224415744ULL);            //         128 B
  if (ws_size < 224415872ULL) return;                          // need ~214 MiB

  gc_prep2<<<513, 256, 0, stream>>>(adp, W1, b1, W2, b2, Af, G2, Ub, bias);
  gc_sq2<<<512, 256, 0, stream>>>(Af, G2);
  gc_mix6<<<1024, 256, 0, stream>>>(x, Ub, Pg);
  gc_gemm13<<<672, 256, 0, stream>>>(G2, Pg, bias, out);
}

// Round 14
// 261.383 us; speedup vs baseline: 1.1696x; 1.1365x over previous
//
#include <hip/hip_runtime.h>
#include <stdint.h>

// Problem dims
#define BDIM 8
#define CDIM 32
#define NDIM 512
#define TDIM 168
#define KG   2048          // GEMM K = 4 slices * 512 nodes
#define NJ   43008         // 1344 (b,l) * 32 o   (column order jj = (b*168+l)*32 + o)
#define ALPHA_ 0.05f
#define BETA_  0.95f

typedef __attribute__((ext_vector_type(8))) short short8;
typedef __attribute__((ext_vector_type(4))) float f32x4;
typedef __attribute__((ext_vector_type(2))) float f2v;
typedef __attribute__((ext_vector_type(4))) unsigned short u16x4;

__device__ __forceinline__ unsigned short f2bf(float f) {
  union { float f; unsigned int u; } v; v.f = f;
  unsigned int r = v.u + 0x7fffu + ((v.u >> 16) & 1u);
  return (unsigned short)(r >> 16);
}
__device__ __forceinline__ float bf2f(unsigned short h) {
  union { unsigned int u; float f; } v; v.u = ((unsigned int)h) << 16;
  return v.f;
}
__device__ __forceinline__ void gload_lds16(const void* g, void* l) {
  __builtin_amdgcn_global_load_lds((const __attribute__((address_space(1))) void*)g,
                                   (__attribute__((address_space(3))) void*)l, 16, 0, 0);
}

// ---- fused prep+build (+ucat in block 512): row/col sums, normalized A/A' -> G2+Af ----
__global__ void gc_prep2(const float* __restrict__ adp,
                         const float* __restrict__ W1, const float* __restrict__ b1,
                         const float* __restrict__ W2, const float* __restrict__ b2,
                         float* __restrict__ Af, unsigned short* __restrict__ G2,
                         unsigned short* __restrict__ Ub, float* __restrict__ bias) {
  int t = threadIdx.x;
  if (blockIdx.x == 512) {   // ucat
    for (int idx = t; idx < 160 * 32; idx += 256) {
      int ko = idx >> 5, c = idx & 31, o = ko & 31, s = ko >> 5;
      float v;
      if (s == 0)      v = BETA_ * (W1[o * 96 + 32 + c] + ALPHA_ * W1[o * 96 + 64 + c]);
      else if (s == 1) v = BETA_ * BETA_ * W1[o * 96 + 64 + c];
      else if (s == 2) v = BETA_ * (W2[o * 96 + 32 + c] + ALPHA_ * W2[o * 96 + 64 + c]);
      else if (s == 3) v = BETA_ * BETA_ * W2[o * 96 + 64 + c];
      else             v = W1[o * 96 + c] + ALPHA_ * (W1[o * 96 + 32 + c] + W1[o * 96 + 64 + c])
                         + W2[o * 96 + c] + ALPHA_ * (W2[o * 96 + 32 + c] + W2[o * 96 + 64 + c]);
      Ub[idx] = f2bf(v);
    }
    if (t < 32) bias[t] = b1[t] + b2[t];
    return;
  }
  int v = blockIdx.x;
  float sA = 0.f, sB = 0.f;
  for (int w = t; w < NDIM; w += 256) { sA += adp[v * NDIM + w]; sB += adp[w * NDIM + v]; }
  __shared__ float red[2][256];
  red[0][t] = sA; red[1][t] = sB; __syncthreads();
  for (int s = 128; s > 0; s >>= 1) {
    if (t < s) { red[0][t] += red[0][t + s]; red[1][t] += red[1][t + s]; }
    __syncthreads();
  }
  float ra = 1.f / (1.f + red[0][0]);
  float rb = 1.f / (1.f + red[1][0]);
  for (int w = t; w < NDIM; w += 256) {
    float d = (v == w) ? 1.f : 0.f;
    float a  = (adp[v * NDIM + w] + d) * ra;   // A[v][w]
    float a2 = (adp[w * NDIM + v] + d) * rb;   // A'[v][w]
    Af[(size_t)v * NDIM + w] = a;
    Af[(size_t)NDIM * NDIM + (size_t)v * NDIM + w] = a2;
    G2[(size_t)(((0 * 64) + (w >> 3)) * 512 + v) * 8 + (w & 7)] = f2bf(a);
    G2[(size_t)(((2 * 64) + (w >> 3)) * 512 + v) * 8 + (w & 7)] = f2bf(a2);
  }
}

// ---- A^2 (slice 1) and A'^2 (slice 3) into G2; 512 blocks of 32x32 tiles ----
__global__ __launch_bounds__(256, 4) void gc_sq2(const float* __restrict__ Af,
                                                 unsigned short* __restrict__ G2) {
  int bid = blockIdx.x;
  int mat = bid >> 8, tile = bid & 255;
  int v0 = (tile >> 4) * 32, w0 = (tile & 15) * 32;
  const float* M = Af + (size_t)mat * NDIM * NDIM;
  __shared__ float T1[64][33];
  __shared__ float T2[64][33];
  int t = threadIdx.x;
  int ty = t >> 4, tx = t & 15;
  float a00 = 0.f, a01 = 0.f, a10 = 0.f, a11 = 0.f;
  for (int u0 = 0; u0 < NDIM; u0 += 64) {
    #pragma unroll
    for (int q = 0; q < 8; ++q) {
      int id = q * 256 + t;
      int c = id & 63, r = id >> 6;
      T1[c][r] = M[(size_t)(v0 + r) * NDIM + u0 + c];
      int u = id >> 5, w = id & 31;
      T2[u][w] = M[(size_t)(u0 + u) * NDIM + w0 + w];
    }
    __syncthreads();
    for (int u = 0; u < 64; ++u) {
      f2v a = *(const f2v*)&T1[u][ty * 2];
      f2v b = *(const f2v*)&T2[u][tx * 2];
      a00 += a[0] * b[0]; a01 += a[0] * b[1];
      a10 += a[1] * b[0]; a11 += a[1] * b[1];
    }
    __syncthreads();
  }
  int sl = mat ? 3 : 1;
  int v = v0 + ty * 2, w = w0 + tx * 2;
  size_t cb = (size_t)(sl * 64 + (w >> 3)) * 512;
  size_t cb1 = (size_t)(sl * 64 + ((w + 1) >> 3)) * 512;
  G2[(cb  + v    ) * 8 + (w & 7)]       = f2bf(a00);
  G2[(cb1 + v    ) * 8 + ((w + 1) & 7)] = f2bf(a01);
  G2[(cb  + v + 1) * 8 + (w & 7)]       = f2bf(a10);
  G2[(cb1 + v + 1) * 8 + ((w + 1) & 7)] = f2bf(a11);
}

// ---- channel-mix via MFMA, direct stores in (b,l,o)-major column order ----
// Pg[kbg 0..320)[jj][8w]; slices 0..3 = GEMM B-panel, slice 4 = identity residual.
// grid 1024 = 8 b * 32 wt(16 w) * 4 lq(42 l); 256 threads (4 waves)
__global__ __launch_bounds__(256, 2) void gc_mix6(const float* __restrict__ x,
    const unsigned short* __restrict__ Ub, unsigned short* __restrict__ Pg) {
  __shared__ __align__(16) unsigned short xs[26880];  // [42 ll][16 w'][40 c pad]
  int bid = blockIdx.x;
  int lq = bid & 3, wt = (bid >> 2) & 31, b = bid >> 7;
  int l0 = lq * 42, w0 = wt * 16;
  int tid = threadIdx.x, wv = tid >> 6, lane = tid & 63;
  int l15 = lane & 15, hi = lane >> 4;

  // stage x[b][:][w0..w0+16)[l0..l0+42) -> xs (coalesced reads, swizzled 2B writes)
  #pragma unroll 4
  for (int e = 0; e < 84; ++e) {
    int id = e * 256 + tid;
    int c = id / 672, rem = id - c * 672;
    int w = rem / 42, ll = rem - w * 42;
    float v = x[(size_t)((b * 32 + c) * 512 + w0 + w) * 168 + l0 + ll];
    xs[(ll * 16 + (w ^ (ll & 15))) * 40 + c] = f2bf(v);
  }
  __syncthreads();

  short8 uF[10];
  #pragma unroll
  for (int mt = 0; mt < 10; ++mt)
    uF[mt] = *(const short8*)(Ub + (size_t)(mt * 16 + l15) * 32 + hi * 8);

  for (int i = 0; i < 11; ++i) {
    int li = wv + 4 * i;
    if (li >= 42) break;
    int l = l0 + li;
    short8 xf = *(const short8*)&xs[(li * 16 + (l15 ^ (li & 15))) * 40 + hi * 8];
    size_t jbase = (size_t)(b * 168 + l) * 32;
    #pragma unroll
    for (int mt = 0; mt < 10; ++mt) {
      f32x4 z = {0.f, 0.f, 0.f, 0.f};
      f32x4 p = __builtin_amdgcn_mfma_f32_16x16x32_bf16(xf, uF[mt], z, 0, 0, 0);
      size_t kbg = (size_t)((mt >> 1) * 64 + wt * 2 + (hi >> 1));
      size_t jj = jbase + ((mt & 1) << 4) + l15;
      u16x4 pk = { f2bf(p[0]), f2bf(p[1]), f2bf(p[2]), f2bf(p[3]) };
      *(u16x4*)(Pg + (kbg * NJ + jj) * 8 + (hi & 1) * 4) = pk;
    }
  }
}

// ---- main GEMM (best-measured r9 structure, setprio removed per m190) ----
// C[512 n][43008 jj] = G[512][2048] * P; epilogue adds P4 + bias via LDS slab.
// BM=256 BN=128 BK=32, 256 threads = 4 waves (2M x 2N), wave tile 128x64.
// TRIPLE-buffered LDS (72KB, 2 blocks/CU): tile t+2 overwrites tile t-1's buffer
// (reads completed last iter) -> one counted vmcnt(6) + one s_barrier per K-tile.
__global__ __launch_bounds__(256, 2) void gc_gemm9b(const unsigned short* __restrict__ G2,
    const unsigned short* __restrict__ Pg, const float* __restrict__ bias,
    float* __restrict__ out) {
  int bid = blockIdx.x;
  int swz = (bid & 7) * 84 + (bid >> 3);   // XCD-chunked bijective swizzle (672 = 8*84)
  int mt = swz & 1, jt = swz >> 1;         // mt fastest: B-panel pair adjacent on same XCD
  int n0 = mt * 256, jj0 = jt * 128;

  __shared__ __align__(16) unsigned short SH[36864];   // 72 KB
  unsigned short* AbBase = SH;            // 3 bufs x [kb 4][n 256][8] = 3 x 8192
  unsigned short* BbBase = SH + 24576;    // 3 bufs x [kb 4][j 128][8] = 3 x 4096

  int tid = threadIdx.x, lane = tid & 63, wid = tid >> 6;
  int wm = wid >> 1, wn = wid & 1;
  int l15 = lane & 15, hi = lane >> 4;

  const unsigned short* srcA[4]; int dA[4];
  #pragma unroll
  for (int q = 0; q < 4; ++q) {
    int f = q * 256 + tid;                       // kb = f>>8, nloc = f&255
    srcA[q] = G2 + ((size_t)(f >> 8) * 512 + n0 + (f & 255)) * 8;
    dA[q] = f * 8;
  }
  const unsigned short* srcB[2]; int dB[2];
  #pragma unroll
  for (int q = 0; q < 2; ++q) {
    int g = q * 256 + tid;                       // kb = g>>7, jloc = g&127
    srcB[q] = Pg + ((size_t)(g >> 7) * NJ + jj0 + (g & 127)) * 8;
    dB[q] = g * 8;
  }
  const size_t strideA = 4 * 512 * 8;            // shorts per K-tile of 32
  const size_t strideB = (size_t)4 * NJ * 8;

  f32x4 acc[8][4] = {};

  // prologue: tiles 0 -> buf0, 1 -> buf1 (12 loads in flight)
  #pragma unroll
  for (int q = 0; q < 4; ++q) gload_lds16(srcA[q], AbBase + dA[q]);
  #pragma unroll
  for (int q = 0; q < 2; ++q) gload_lds16(srcB[q], BbBase + dB[q]);
  #pragma unroll
  for (int q = 0; q < 4; ++q) gload_lds16(srcA[q] + strideA, AbBase + 8192 + dA[q]);
  #pragma unroll
  for (int q = 0; q < 2; ++q) gload_lds16(srcB[q] + strideB, BbBase + 4096 + dB[q]);

  int aoffs = (wm * 128 + l15) * 8;
  int boffs = (wn * 64 + l15) * 8;

  int cur = 0;
  for (int t = 0; t < 64; ++t) {
    if (t < 63) { asm volatile("s_waitcnt vmcnt(6)" ::: "memory"); }
    else        { asm volatile("s_waitcnt vmcnt(0)" ::: "memory"); }
    __builtin_amdgcn_s_barrier();                // tile t (buf[cur]) staged by all waves

    if (t < 62) {                                // stage t+2 into buffer of tile t-1
      int nxt = cur - 1; if (nxt < 0) nxt = 2;
      #pragma unroll
      for (int q = 0; q < 4; ++q)
        gload_lds16(srcA[q] + (size_t)(t + 2) * strideA, AbBase + nxt * 8192 + dA[q]);
      #pragma unroll
      for (int q = 0; q < 2; ++q)
        gload_lds16(srcB[q] + (size_t)(t + 2) * strideB, BbBase + nxt * 4096 + dB[q]);
    }

    const unsigned short* ap = AbBase + cur * 8192;
    const unsigned short* bp = BbBase + cur * 4096;
    short8 aF[8], bF[4];
    #pragma unroll
    for (int mi = 0; mi < 8; ++mi)
      aF[mi] = *(const short8*)&ap[hi * 2048 + aoffs + mi * 128];
    #pragma unroll
    for (int nj = 0; nj < 4; ++nj)
      bF[nj] = *(const short8*)&bp[hi * 1024 + boffs + nj * 128];

    #pragma unroll
    for (int mi = 0; mi < 8; ++mi)
      #pragma unroll
      for (int nj = 0; nj < 4; ++nj)
        acc[mi][nj] = __builtin_amdgcn_mfma_f32_16x16x32_bf16(aF[mi], bF[nj], acc[mi][nj], 0, 0, 0);

    cur = cur + 1; if (cur == 3) cur = 0;
  }

  // ---- epilogue: 4 slabs of 64 n; LDS transpose; out = C + P4 + bias ----
  int bl0 = jt * 4;                              // 4 consecutive (b,l), same b (168%4==0)
  int bq = bl0 / 168, l0g = bl0 - bq * 168;
  float* Cs = (float*)SH;                        // 64*132*4 = 33.8KB <= 72KB
  int o = tid & 31, nl8 = tid >> 5;              // o 0..31, nl8 0..7
  float bs = bias[o];
  __syncthreads();
  for (int s = 0; s < 4; ++s) {
    if (wm == (s >> 1)) {
      int mio = (s & 1) * 4;
      #pragma unroll
      for (int mi = 0; mi < 4; ++mi)
        #pragma unroll
        for (int nj = 0; nj < 4; ++nj) {
          int row = mi * 16 + hi * 4;
          int col = wn * 64 + nj * 16 + l15;
          #pragma unroll
          for (int r = 0; r < 4; ++r)
            Cs[(row + r) * 132 + col] = acc[mio + mi][nj][r];
        }
    }
    __syncthreads();
    int n_g0 = n0 + s * 64 + nl8 * 8;
    const unsigned short* p4c =
        Pg + (((size_t)256 + (n_g0 >> 3)) * NJ + (size_t)bl0 * 32 + o) * 8;
    short8 pv0 = *(const short8*)(p4c);
    short8 pv1 = *(const short8*)(p4c + 256);    // l+1 (jj stride 32 chunks)
    short8 pv2 = *(const short8*)(p4c + 512);    // l+2
    short8 pv3 = *(const short8*)(p4c + 768);    // l+3
    #pragma unroll
    for (int q = 0; q < 8; ++q) {
      int nr = nl8 * 8 + q;
      int n_g = n_g0 + q;
      float v0 = Cs[nr * 132 +  0 + o] + bf2f((unsigned short)pv0[q]) + bs;
      float v1 = Cs[nr * 132 + 32 + o] + bf2f((unsigned short)pv1[q]) + bs;
      float v2 = Cs[nr * 132 + 64 + o] + bf2f((unsigned short)pv2[q]) + bs;
      float v3 = Cs[nr * 132 + 96 + o] + bf2f((unsigned short)pv3[q]) + bs;
      f32x4 vv = {v0, v1, v2, v3};
      *(f32x4*)(out + ((size_t)(bq * 32 + o) * 512 + n_g) * 168 + l0g) = vv;
    }
    __syncthreads();
  }
}

extern "C" void kernel_launch(void* const* d_in, const int* in_sizes, int n_in,
                              void* d_out, int out_size, void* d_ws, size_t ws_size,
                              hipStream_t stream) {
  const float* x   = (const float*)d_in[0];
  const float* adp = (const float*)d_in[1];
  const float* W1  = (const float*)d_in[2];
  const float* b1  = (const float*)d_in[3];
  const float* W2  = (const float*)d_in[4];
  const float* b2  = (const float*)d_in[5];
  float* out = (float*)d_out;

  char* w = (char*)d_ws;
  unsigned short* Pg  = (unsigned short*)(w);                  // 220,200,960 B (5 slices)
  unsigned short* G2  = (unsigned short*)(w + 220200960ULL);   //   2,097,152 B
  float* Af           = (float*)(w + 222298112ULL);            //   2,097,152 B
  unsigned short* Ub  = (unsigned short*)(w + 224399360ULL);   //      16,384 B (10,240 used)
  float* bias         = (float*)(w + 224415744ULL);            //         128 B
  if (ws_size < 224415872ULL) return;                          // need ~214 MiB

  gc_prep2<<<513, 256, 0, stream>>>(adp, W1, b1, W2, b2, Af, G2, Ub, bias);
  gc_sq2<<<512, 256, 0, stream>>>(Af, G2);
  gc_mix6<<<1024, 256, 0, stream>>>(x, Ub, Pg);
  gc_gemm9b<<<672, 256, 0, stream>>>(G2, Pg, bias, out);
}